// Round 2
// baseline (255.540 us; speedup 1.0000x reference)
//
#include <hip/hip_runtime.h>
#include <hip/hip_bf16.h>

// EdgeDetourHead: B=2, N=512, E=128, H=256
// h1 = relu( [ |h_i-h_j| | h_j | e_ij*1 | 1 ] @ [W1c; W1b; w1d; 0] + PA[i] )
//      (PB, e*w1d folded into the MFMA K-dim; PA=h_i@W1a+b1 stays fp32)
// h2 = relu( [h1 | 1] @ [W2; b2] )
// p  = h2 @ W3 + b3 ; out = 0.5*(p+p^T), zero diag

#define BN 512
#define EE 128
#define HH 256

typedef __attribute__((ext_vector_type(8)))  short short8;
typedef __attribute__((ext_vector_type(16))) float f32x16;
typedef __attribute__((ext_vector_type(4)))  float f32x4;

static __device__ __forceinline__ unsigned short f2bf(float f) {
    __bf16 h = (__bf16)f;                       // RNE fptrunc -> v_cvt_*bf16 on gfx950
    return __builtin_bit_cast(unsigned short, h);
}
static __device__ __forceinline__ float bf2f(unsigned short s) {
    return (float)__builtin_bit_cast(__bf16, s);
}
static __device__ __forceinline__ f32x16 zero16() {
    f32x16 v;
    #pragma unroll
    for (int i = 0; i < 16; ++i) v[i] = 0.f;
    return v;
}
#define MFMA(a, b, c) __builtin_amdgcn_mfma_f32_32x32x16_bf16((a), (b), (c), 0, 0, 0)

// ---------------- kernel 0: pack everything into MFMA fragment order ----------------
// B-frag (32x32x16): lane l holds B[k=(l>>5)*8+t][n=l&31], t=0..7.
// A-frag:            lane l holds A[m=l&31][k=(l>>5)*8+t].
// Packed linear idx: ((frag_id)*64 + l)*8 + t  -> dwordx4 per lane, coalesced.
__global__ void pack_all(const float* __restrict__ node, const float* __restrict__ W1,
                         const float* __restrict__ W2, const float* __restrict__ b2,
                         unsigned short* __restrict__ w1c_p, unsigned short* __restrict__ w1b_p,
                         unsigned short* __restrict__ w2_p,  unsigned short* __restrict__ w1d_f,
                         unsigned short* __restrict__ b2_f,  unsigned short* __restrict__ node_p) {
    int idx = blockIdx.x * 256 + threadIdx.x;          // 0..131071
    {   // node A-frags: frag (b, j32 0..15, kb 0..7)
        int t = idx & 7, l = (idx >> 3) & 63, kb = (idx >> 9) & 7;
        int j32 = (idx >> 12) & 15, b = (idx >> 16) & 1;
        int j = j32 * 32 + (l & 31), e = kb * 16 + (l >> 5) * 8 + t;
        node_p[idx] = f2bf(node[((size_t)b * BN + j) * EE + e]);
    }
    if (idx < 65536) {                                 // W2: kb 0..15
        int t = idx & 7, l = (idx >> 3) & 63, nb = (idx >> 9) & 7, kb = idx >> 12;
        int k = kb * 16 + (l >> 5) * 8 + t, n = nb * 32 + (l & 31);
        w2_p[idx] = f2bf(W2[k * HH + n]);
        if (idx < 32768) {                             // W1c rows 256..383, W1b rows 128..255
            w1c_p[idx] = f2bf(W1[(2 * EE + k) * HH + n]);
            w1b_p[idx] = f2bf(W1[(EE + k) * HH + n]);
        }
    }
    if (idx < 4096) {                                  // rank-1 B-frags: w1d (row 384), b2
        int t = idx & 7, l = (idx >> 3) & 63, nb = idx >> 9;
        int n = nb * 32 + (l & 31);
        bool nz = (t == 0 && l < 32);
        w1d_f[idx] = nz ? f2bf(W1[(3 * EE) * HH + n]) : (unsigned short)0;
        b2_f[idx]  = nz ? f2bf(b2[n]) : (unsigned short)0;
    }
}

// ---------------- kernel 1: PA = h@W1a + b1 (fp32, exact) ----------------
__global__ void precompute_pa(const float* __restrict__ node, const float* __restrict__ W1,
                              const float* __restrict__ b1, float* __restrict__ PA) {
    int bi = blockIdx.x, h = threadIdx.x;
    const float* nd = node + (size_t)bi * EE;
    float sa = b1[h];
    #pragma unroll 8
    for (int e = 0; e < EE; ++e) sa += nd[e] * W1[e * HH + h];
    PA[bi * HH + h] = sa;
}

// ---------------- kernel 2: fused main ----------------
// One WG = (b, i) x 64 j. 4 waves; wave w owns h-cols [w*64, w*64+64).
// Single LDS buffer aliases D (stride 136 shorts) then h1/h2 (stride 264 shorts).
__global__ __launch_bounds__(256, 3) void edge_main(
    const float* __restrict__ node, const float* __restrict__ euclid,
    const float* __restrict__ W3, const float* __restrict__ b3,
    const float* __restrict__ PA,
    const unsigned short* __restrict__ w1c_p, const unsigned short* __restrict__ w1b_p,
    const unsigned short* __restrict__ w2_p,  const unsigned short* __restrict__ w1d_f,
    const unsigned short* __restrict__ b2_f,  const unsigned short* __restrict__ node_p,
    float* __restrict__ out)
{
    __shared__ __align__(16) unsigned short lds_buf[64 * 264];  // 33792 B: D then h1/h2
    __shared__ __align__(16) float hi_f[EE];                    // 512 B
    __shared__ float pp[256];                                   // 1 KB layer-3 partials

    const int jt = blockIdx.x, i = blockIdx.y, b = blockIdx.z;
    const int jbase = jt * 64;
    const int tid = threadIdx.x, wave = tid >> 6, lane = tid & 63;
    const int m0 = lane & 31, kq = (lane >> 5) * 8;

    if (tid < 32)
        ((f32x4*)hi_f)[tid] = ((const f32x4*)(node + ((size_t)b * BN + i) * EE))[tid];
    __syncthreads();

    // ---- build D = |h_i - h_j| bf16, 64x128, stride 136 ----
    {
        int row = tid >> 2, q = tid & 3;
        const f32x4* nj = (const f32x4*)(node + ((size_t)b * BN + jbase + row) * EE);
        const f32x4* hv = (const f32x4*)hi_f;
        unsigned short* dst = &lds_buf[row * 136 + q * 32];
        #pragma unroll
        for (int k = 0; k < 4; ++k) {
            f32x4 a0 = nj[q * 8 + k * 2 + 0], h0 = hv[q * 8 + k * 2 + 0];
            f32x4 a1 = nj[q * 8 + k * 2 + 1], h1v = hv[q * 8 + k * 2 + 1];
            short8 pk;
            #pragma unroll
            for (int u = 0; u < 4; ++u) {
                pk[u]     = (short)f2bf(fabsf(a0[u] - h0[u]));
                pk[4 + u] = (short)f2bf(fabsf(a1[u] - h1v[u]));
            }
            *(short8*)(dst + k * 8) = pk;
        }
    }
    __syncthreads();

    // ---- layer 1: D@W1c + hj@W1b + e*w1d (all in MFMA) ----
    f32x16 a00 = zero16(), a01 = zero16(), a10 = zero16(), a11 = zero16();
    {
        const short8* bc = (const short8*)w1c_p;
        const short8* bb = (const short8*)w1b_p;
        const short8* np = (const short8*)node_p + (size_t)(b * 16 + jt * 2) * 8 * 64;
        #pragma unroll
        for (int kb = 0; kb < 8; ++kb) {
            short8 ad0 = *(const short8*)&lds_buf[m0 * 136 + kb * 16 + kq];
            short8 ad1 = *(const short8*)&lds_buf[(m0 + 32) * 136 + kb * 16 + kq];
            short8 ah0 = np[kb * 64 + lane];
            short8 ah1 = np[(8 + kb) * 64 + lane];
            short8 b0 = bc[(kb * 8 + wave * 2 + 0) * 64 + lane];
            short8 b1 = bc[(kb * 8 + wave * 2 + 1) * 64 + lane];
            short8 c0 = bb[(kb * 8 + wave * 2 + 0) * 64 + lane];
            short8 c1 = bb[(kb * 8 + wave * 2 + 1) * 64 + lane];
            a00 = MFMA(ad0, b0, a00); a01 = MFMA(ad0, b1, a01);
            a10 = MFMA(ad1, b0, a10); a11 = MFMA(ad1, b1, a11);
            a00 = MFMA(ah0, c0, a00); a01 = MFMA(ah0, c1, a01);
            a10 = MFMA(ah1, c0, a10); a11 = MFMA(ah1, c1, a11);
        }
        // rank-1 e*w1d block
        const float* erow = euclid + ((size_t)b * BN + i) * BN + jbase;
        short8 ae0, ae1;
        #pragma unroll
        for (int u = 0; u < 8; ++u) { ae0[u] = 0; ae1[u] = 0; }
        if (lane < 32) {
            ae0[0] = (short)f2bf(erow[m0]);
            ae1[0] = (short)f2bf(erow[32 + m0]);
        }
        short8 d0 = ((const short8*)w1d_f)[(wave * 2 + 0) * 64 + lane];
        short8 d1 = ((const short8*)w1d_f)[(wave * 2 + 1) * 64 + lane];
        a00 = MFMA(ae0, d0, a00); a01 = MFMA(ae0, d1, a01);
        a10 = MFMA(ae1, d0, a10); a11 = MFMA(ae1, d1, a11);
    }
    __syncthreads();   // D dead; safe to overwrite with h1

    // ---- epilogue 1: h1 = relu(acc + PA[i]) -> lds_buf stride 264 ----
    {
        const float* paRow = PA + ((size_t)b * BN + i) * HH;
        int col0 = wave * 64 + m0;
        float pa0 = paRow[col0], pa1 = paRow[col0 + 32];
        int rbase = 4 * (lane >> 5);
        #pragma unroll
        for (int r = 0; r < 16; ++r) {
            int row = (r & 3) + 8 * (r >> 2) + rbase;
            float v0 = a00[r] + pa0; v0 = v0 > 0.f ? v0 : 0.f;
            float v1 = a01[r] + pa1; v1 = v1 > 0.f ? v1 : 0.f;
            float v2 = a10[r] + pa0; v2 = v2 > 0.f ? v2 : 0.f;
            float v3 = a11[r] + pa1; v3 = v3 > 0.f ? v3 : 0.f;
            lds_buf[row * 264 + col0]             = f2bf(v0);
            lds_buf[row * 264 + col0 + 32]        = f2bf(v1);
            lds_buf[(row + 32) * 264 + col0]      = f2bf(v2);
            lds_buf[(row + 32) * 264 + col0 + 32] = f2bf(v3);
        }
    }
    __syncthreads();

    // ---- layer 2: h1@W2 + 1*b2 ----
    f32x16 c00 = zero16(), c01 = zero16(), c10 = zero16(), c11 = zero16();
    {
        const short8* bp = (const short8*)w2_p;
        #pragma unroll
        for (int kb = 0; kb < 16; ++kb) {
            short8 ad0 = *(const short8*)&lds_buf[m0 * 264 + kb * 16 + kq];
            short8 ad1 = *(const short8*)&lds_buf[(m0 + 32) * 264 + kb * 16 + kq];
            short8 b0 = bp[(kb * 8 + wave * 2 + 0) * 64 + lane];
            short8 b1 = bp[(kb * 8 + wave * 2 + 1) * 64 + lane];
            c00 = MFMA(ad0, b0, c00); c01 = MFMA(ad0, b1, c01);
            c10 = MFMA(ad1, b0, c10); c11 = MFMA(ad1, b1, c11);
        }
        short8 aone;
        #pragma unroll
        for (int u = 0; u < 8; ++u) aone[u] = 0;
        if (lane < 32) aone[0] = (short)0x3F80;        // bf16 1.0
        short8 e0 = ((const short8*)b2_f)[(wave * 2 + 0) * 64 + lane];
        short8 e1 = ((const short8*)b2_f)[(wave * 2 + 1) * 64 + lane];
        c00 = MFMA(aone, e0, c00); c01 = MFMA(aone, e1, c01);
        c10 = MFMA(aone, e0, c10); c11 = MFMA(aone, e1, c11);
    }
    __syncthreads();   // h1 dead

    // ---- epilogue 2: h2 = relu(acc) -> lds_buf ----
    {
        int col0 = wave * 64 + m0;
        int rbase = 4 * (lane >> 5);
        #pragma unroll
        for (int r = 0; r < 16; ++r) {
            int row = (r & 3) + 8 * (r >> 2) + rbase;
            float v0 = c00[r] > 0.f ? c00[r] : 0.f;
            float v1 = c01[r] > 0.f ? c01[r] : 0.f;
            float v2 = c10[r] > 0.f ? c10[r] : 0.f;
            float v3 = c11[r] > 0.f ? c11[r] : 0.f;
            lds_buf[row * 264 + col0]             = f2bf(v0);
            lds_buf[row * 264 + col0 + 32]        = f2bf(v1);
            lds_buf[(row + 32) * 264 + col0]      = f2bf(v2);
            lds_buf[(row + 32) * 264 + col0 + 32] = f2bf(v3);
        }
    }
    __syncthreads();

    // ---- layer 3: p = h2 @ W3 + b3 (fp32, 4-way split-K; W3 wave-uniform) ----
    {
        int r = tid & 63, part = tid >> 6, c0 = part * 64;
        float s = 0.f;
        #pragma unroll
        for (int k = 0; k < 8; ++k) {
            short8 h8 = *(const short8*)&lds_buf[r * 264 + c0 + k * 8];
            #pragma unroll
            for (int u = 0; u < 8; ++u)
                s += bf2f((unsigned short)h8[u]) * W3[c0 + k * 8 + u];
        }
        pp[part * 64 + r] = s;
    }
    __syncthreads();
    if (tid < 64) {
        float v = pp[tid] + pp[64 + tid] + pp[128 + tid] + pp[192 + tid] + b3[0];
        out[((size_t)b * BN + i) * BN + jbase + tid] = v;
    }
}

// ---------------- kernel 3: in-place symmetrize + zero diagonal ----------------
__global__ void symmetrize(float* __restrict__ out) {
    int b = blockIdx.z, ti = blockIdx.y, tj = blockIdx.x;
    if (tj < ti) return;
    int i = ti * 32 + threadIdx.y, j = tj * 32 + threadIdx.x;
    float* p = out + (size_t)b * BN * BN;
    if (i == j) { p[(size_t)i * BN + j] = 0.f; return; }
    if (j < i) return;
    float a = p[(size_t)i * BN + j];
    float c = p[(size_t)j * BN + i];
    float v = 0.5f * (a + c);
    p[(size_t)i * BN + j] = v;
    p[(size_t)j * BN + i] = v;
}

extern "C" void kernel_launch(void* const* d_in, const int* in_sizes, int n_in,
                              void* d_out, int out_size, void* d_ws, size_t ws_size,
                              hipStream_t stream) {
    const float* node   = (const float*)d_in[0];
    const float* euclid = (const float*)d_in[2];
    const float* W1     = (const float*)d_in[3];
    const float* b1     = (const float*)d_in[4];
    const float* W2     = (const float*)d_in[5];
    const float* b2     = (const float*)d_in[6];
    const float* W3     = (const float*)d_in[7];
    const float* b3     = (const float*)d_in[8];
    float* out = (float*)d_out;

    char* ws = (char*)d_ws;
    float*          PA     = (float*)ws;                              // 1 MB
    unsigned short* w1c_p  = (unsigned short*)(ws + (1u << 20));               // 64 KB
    unsigned short* w1b_p  = (unsigned short*)(ws + (1u << 20) + 65536);       // 64 KB
    unsigned short* w2_p   = (unsigned short*)(ws + (1u << 20) + 131072);      // 128 KB
    unsigned short* w1d_f  = (unsigned short*)(ws + (1u << 20) + 262144);      // 8 KB
    unsigned short* b2_f   = (unsigned short*)(ws + (1u << 20) + 270336);      // 8 KB
    unsigned short* node_p = (unsigned short*)(ws + (1u << 20) + 278528);      // 256 KB

    pack_all<<<512, 256, 0, stream>>>(node, W1, W2, b2, w1c_p, w1b_p, w2_p, w1d_f, b2_f, node_p);
    precompute_pa<<<BN * 2, 256, 0, stream>>>(node, W1, b1, PA);
    edge_main<<<dim3(BN / 64, BN, 2), 256, 0, stream>>>(
        node, euclid, W3, b3, PA, w1c_p, w1b_p, w2_p, w1d_f, b2_f, node_p, out);
    symmetrize<<<dim3(BN / 32, BN / 32, 2), dim3(32, 32), 0, stream>>>(out);
}

// Round 3
// 243.675 us; speedup vs baseline: 1.0487x; 1.0487x over previous
//
#include <hip/hip_runtime.h>
#include <hip/hip_bf16.h>

// EdgeDetourHead: B=2, N=512, E=128, H=256
// h1 = relu( [ |h_i-h_j| | h_j | e_ij | 1 ] @ [W1c; W1b; w1d; 0] + PA[i] )
// h2 = relu( [h1 | 1] @ [W2; b2] )
// p  = h2 @ W3 + b3 ; out = 0.5*(p+p^T), zero diag
//
// R3 structure: WG = 256 thr (4 waves), tile = one (b,i) x 128 j, N=256.
// Wave w owns cols [w*64, w*64+64): 4 m-tiles x 2 n-tiles = 8 acc (128 VGPR).
// h_j A-frags staged into LDS during D-build (no global A traffic in K-loop).

#define BN 512
#define EE 128
#define HH 256

typedef __attribute__((ext_vector_type(8)))  short short8;
typedef __attribute__((ext_vector_type(16))) float f32x16;
typedef __attribute__((ext_vector_type(4)))  float f32x4;

static __device__ __forceinline__ unsigned short f2bf(float f) {
    __bf16 h = (__bf16)f;
    return __builtin_bit_cast(unsigned short, h);
}
static __device__ __forceinline__ float bf2f(unsigned short s) {
    return (float)__builtin_bit_cast(__bf16, s);
}
static __device__ __forceinline__ f32x16 zero16() {
    f32x16 v;
    #pragma unroll
    for (int i = 0; i < 16; ++i) v[i] = 0.f;
    return v;
}
#define MFMA(a, b, c) __builtin_amdgcn_mfma_f32_32x32x16_bf16((a), (b), (c), 0, 0, 0)

// ---------------- kernel 0: pack weights into MFMA B-fragment order ----------------
// B-frag (32x32x16): lane l holds B[k=(l>>5)*8+t][n=l&31], t=0..7.
// Packed linear idx: (frag_id*64 + l)*8 + t -> dwordx4 per lane.
__global__ void pack_all(const float* __restrict__ W1, const float* __restrict__ W2,
                         const float* __restrict__ b2,
                         unsigned short* __restrict__ w1c_p, unsigned short* __restrict__ w1b_p,
                         unsigned short* __restrict__ w2_p,  unsigned short* __restrict__ w1d_f,
                         unsigned short* __restrict__ b2_f) {
    int idx = blockIdx.x * 256 + threadIdx.x;          // 0..65535
    {                                                  // W2: kb 0..15
        int t = idx & 7, l = (idx >> 3) & 63, nb = (idx >> 9) & 7, kb = idx >> 12;
        int k = kb * 16 + (l >> 5) * 8 + t, n = nb * 32 + (l & 31);
        w2_p[idx] = f2bf(W2[k * HH + n]);
        if (idx < 32768) {                             // W1c rows 256..383, W1b rows 128..255
            w1c_p[idx] = f2bf(W1[(2 * EE + k) * HH + n]);
            w1b_p[idx] = f2bf(W1[(EE + k) * HH + n]);
        }
    }
    if (idx < 4096) {                                  // rank-1 B-frags: w1d (row 384), b2
        int t = idx & 7, l = (idx >> 3) & 63, nb = idx >> 9;
        int n = nb * 32 + (l & 31);
        bool nz = (t == 0 && l < 32);
        w1d_f[idx] = nz ? f2bf(W1[(3 * EE) * HH + n]) : (unsigned short)0;
        b2_f[idx]  = nz ? f2bf(b2[n]) : (unsigned short)0;
    }
}

// ---------------- kernel 1: PA = h@W1a + b1 (fp32, exact) ----------------
__global__ void precompute_pa(const float* __restrict__ node, const float* __restrict__ W1,
                              const float* __restrict__ b1, float* __restrict__ PA) {
    int bi = blockIdx.x, h = threadIdx.x;
    const float* nd = node + (size_t)bi * EE;
    float sa = b1[h];
    #pragma unroll 8
    for (int e = 0; e < EE; ++e) sa += nd[e] * W1[e * HH + h];
    PA[bi * HH + h] = sa;
}

// ---------------- kernel 2: fused main ----------------
__global__ __launch_bounds__(256, 2) void edge_main(
    const float* __restrict__ node, const float* __restrict__ euclid,
    const float* __restrict__ W3, const float* __restrict__ b3,
    const float* __restrict__ PA,
    const unsigned short* __restrict__ w1c_p, const unsigned short* __restrict__ w1b_p,
    const unsigned short* __restrict__ w2_p,  const unsigned short* __restrict__ w1d_f,
    const unsigned short* __restrict__ b2_f,
    float* __restrict__ out)
{
    // h1/h2 region: 128 rows x 264 shorts = 67584 B.
    // During phase 1: D (128x136 = 17408 shorts) + hj-frags (16384 shorts) alias it exactly.
    __shared__ __align__(16) unsigned short lds_buf[128 * 264];
    __shared__ __align__(16) float hi_f[EE];
    __shared__ float lds_e[128];
    __shared__ float pp[256];

    const int jt = blockIdx.x, i = blockIdx.y, b = blockIdx.z;
    const int jbase = jt * 128;
    const int tid = threadIdx.x, wave = tid >> 6, lane = tid & 63;
    const int m0 = lane & 31, q = lane >> 5, kq = q * 8;
    unsigned short* hjb = lds_buf + 128 * 136;

    if (tid < 32)
        ((f32x4*)hi_f)[tid] = ((const f32x4*)(node + ((size_t)b * BN + i) * EE))[tid];
    if (tid < 128)
        lds_e[tid] = euclid[((size_t)b * BN + i) * BN + jbase + tid];
    __syncthreads();

    // ---- phase 1: build D = |h_i-h_j| (row-major, stride 136) and hj bf16 A-frags ----
    {
        int row = tid >> 1, half = tid & 1;
        const f32x4* nj = (const f32x4*)(node + ((size_t)b * BN + jbase + row) * EE);
        const f32x4* hv = (const f32x4*)hi_f;
        int mt = row >> 5, r31 = row & 31;
        #pragma unroll
        for (int g = 0; g < 8; ++g) {
            int c0 = half * 64 + g * 8;
            f32x4 a0 = nj[c0 / 4], a1 = nj[c0 / 4 + 1];
            f32x4 h0 = hv[c0 / 4], h1v = hv[c0 / 4 + 1];
            short8 pd, ph;
            #pragma unroll
            for (int u = 0; u < 4; ++u) {
                pd[u]     = (short)f2bf(fabsf(a0[u] - h0[u]));
                pd[4 + u] = (short)f2bf(fabsf(a1[u] - h1v[u]));
                ph[u]     = (short)f2bf(a0[u]);
                ph[4 + u] = (short)f2bf(a1[u]);
            }
            *(short8*)&lds_buf[row * 136 + c0] = pd;
            int kb = c0 >> 4, hk = (c0 >> 3) & 1;
            *(short8*)&hjb[((mt * 8 + kb) * 64 + r31 + 32 * hk) * 8] = ph;
        }
    }
    __syncthreads();

    // ---- layer 1: D@W1c + hj@W1b + e*w1d ----
    f32x16 acc[4][2];
    #pragma unroll
    for (int mt = 0; mt < 4; ++mt) { acc[mt][0] = zero16(); acc[mt][1] = zero16(); }
    {
        const short8* bc  = (const short8*)w1c_p;
        const short8* bb  = (const short8*)w1b_p;
        const short8* hjf = (const short8*)hjb;
        #pragma unroll
        for (int kb = 0; kb < 8; ++kb) {
            short8 b0 = bc[(kb * 8 + wave * 2 + 0) * 64 + lane];
            short8 b1 = bc[(kb * 8 + wave * 2 + 1) * 64 + lane];
            short8 c0 = bb[(kb * 8 + wave * 2 + 0) * 64 + lane];
            short8 c1 = bb[(kb * 8 + wave * 2 + 1) * 64 + lane];
            #pragma unroll
            for (int mt = 0; mt < 4; ++mt) {
                short8 ad = *(const short8*)&lds_buf[(mt * 32 + m0) * 136 + kb * 16 + kq];
                short8 ah = hjf[(mt * 8 + kb) * 64 + lane];
                acc[mt][0] = MFMA(ad, b0, acc[mt][0]);
                acc[mt][1] = MFMA(ad, b1, acc[mt][1]);
                acc[mt][0] = MFMA(ah, c0, acc[mt][0]);
                acc[mt][1] = MFMA(ah, c1, acc[mt][1]);
            }
        }
        // rank-1 e*w1d
        short8 d0 = ((const short8*)w1d_f)[(wave * 2 + 0) * 64 + lane];
        short8 d1 = ((const short8*)w1d_f)[(wave * 2 + 1) * 64 + lane];
        #pragma unroll
        for (int mt = 0; mt < 4; ++mt) {
            short8 ae;
            #pragma unroll
            for (int u = 0; u < 8; ++u) ae[u] = 0;
            if (lane < 32) ae[0] = (short)f2bf(lds_e[mt * 32 + m0]);
            acc[mt][0] = MFMA(ae, d0, acc[mt][0]);
            acc[mt][1] = MFMA(ae, d1, acc[mt][1]);
        }
    }
    __syncthreads();   // D + hj dead

    // ---- epilogue 1: h1 = relu(acc + PA[i]) -> lds_buf stride 264 ----
    {
        const float* paRow = PA + ((size_t)b * BN + i) * HH;
        int col0 = wave * 64 + m0;
        float pa0 = paRow[col0], pa1 = paRow[col0 + 32];
        int rq = 4 * q;
        #pragma unroll
        for (int mt = 0; mt < 4; ++mt) {
            #pragma unroll
            for (int r = 0; r < 16; ++r) {
                int row = mt * 32 + (r & 3) + 8 * (r >> 2) + rq;
                float v0 = acc[mt][0][r] + pa0; v0 = v0 > 0.f ? v0 : 0.f;
                float v1 = acc[mt][1][r] + pa1; v1 = v1 > 0.f ? v1 : 0.f;
                lds_buf[row * 264 + col0]      = f2bf(v0);
                lds_buf[row * 264 + col0 + 32] = f2bf(v1);
            }
        }
    }
    __syncthreads();

    // ---- layer 2: h1@W2 + 1*b2 ----
    f32x16 c2[4][2];
    #pragma unroll
    for (int mt = 0; mt < 4; ++mt) { c2[mt][0] = zero16(); c2[mt][1] = zero16(); }
    {
        const short8* bp = (const short8*)w2_p;
        #pragma unroll
        for (int kb = 0; kb < 16; ++kb) {
            short8 b0 = bp[(kb * 8 + wave * 2 + 0) * 64 + lane];
            short8 b1 = bp[(kb * 8 + wave * 2 + 1) * 64 + lane];
            #pragma unroll
            for (int mt = 0; mt < 4; ++mt) {
                short8 a = *(const short8*)&lds_buf[(mt * 32 + m0) * 264 + kb * 16 + kq];
                c2[mt][0] = MFMA(a, b0, c2[mt][0]);
                c2[mt][1] = MFMA(a, b1, c2[mt][1]);
            }
        }
        short8 aone;
        #pragma unroll
        for (int u = 0; u < 8; ++u) aone[u] = 0;
        if (lane < 32) aone[0] = (short)0x3F80;        // bf16 1.0
        short8 e0 = ((const short8*)b2_f)[(wave * 2 + 0) * 64 + lane];
        short8 e1 = ((const short8*)b2_f)[(wave * 2 + 1) * 64 + lane];
        #pragma unroll
        for (int mt = 0; mt < 4; ++mt) {
            c2[mt][0] = MFMA(aone, e0, c2[mt][0]);
            c2[mt][1] = MFMA(aone, e1, c2[mt][1]);
        }
    }
    __syncthreads();   // h1 dead

    // ---- epilogue 2: h2 = relu(c2) -> lds_buf ----
    {
        int col0 = wave * 64 + m0;
        int rq = 4 * q;
        #pragma unroll
        for (int mt = 0; mt < 4; ++mt) {
            #pragma unroll
            for (int r = 0; r < 16; ++r) {
                int row = mt * 32 + (r & 3) + 8 * (r >> 2) + rq;
                float v0 = c2[mt][0][r] > 0.f ? c2[mt][0][r] : 0.f;
                float v1 = c2[mt][1][r] > 0.f ? c2[mt][1][r] : 0.f;
                lds_buf[row * 264 + col0]      = f2bf(v0);
                lds_buf[row * 264 + col0 + 32] = f2bf(v1);
            }
        }
    }
    __syncthreads();

    // ---- layer 3: p = h2 @ W3 + b3 (fp32, 2-way split-K) ----
    {
        int row = tid >> 1, halfc = (tid & 1) * 128;
        float s = 0.f;
        #pragma unroll
        for (int k = 0; k < 16; ++k) {
            short8 h8 = *(const short8*)&lds_buf[row * 264 + halfc + k * 8];
            #pragma unroll
            for (int u = 0; u < 8; ++u)
                s += bf2f((unsigned short)h8[u]) * W3[halfc + k * 8 + u];
        }
        pp[tid] = s;
    }
    __syncthreads();
    if (tid < 128) {
        float v = pp[tid * 2] + pp[tid * 2 + 1] + b3[0];
        out[((size_t)b * BN + i) * BN + jbase + tid] = v;
    }
}

// ---------------- kernel 3: in-place symmetrize + zero diagonal ----------------
__global__ void symmetrize(float* __restrict__ out) {
    int b = blockIdx.z, ti = blockIdx.y, tj = blockIdx.x;
    if (tj < ti) return;
    int i = ti * 32 + threadIdx.y, j = tj * 32 + threadIdx.x;
    float* p = out + (size_t)b * BN * BN;
    if (i == j) { p[(size_t)i * BN + j] = 0.f; return; }
    if (j < i) return;
    float a = p[(size_t)i * BN + j];
    float c = p[(size_t)j * BN + i];
    float v = 0.5f * (a + c);
    p[(size_t)i * BN + j] = v;
    p[(size_t)j * BN + i] = v;
}

extern "C" void kernel_launch(void* const* d_in, const int* in_sizes, int n_in,
                              void* d_out, int out_size, void* d_ws, size_t ws_size,
                              hipStream_t stream) {
    const float* node   = (const float*)d_in[0];
    const float* euclid = (const float*)d_in[2];
    const float* W1     = (const float*)d_in[3];
    const float* b1     = (const float*)d_in[4];
    const float* W2     = (const float*)d_in[5];
    const float* b2     = (const float*)d_in[6];
    const float* W3     = (const float*)d_in[7];
    const float* b3     = (const float*)d_in[8];
    float* out = (float*)d_out;

    char* ws = (char*)d_ws;
    float*          PA    = (float*)ws;                              // 1 MB
    unsigned short* w1c_p = (unsigned short*)(ws + (1u << 20));               // 64 KB
    unsigned short* w1b_p = (unsigned short*)(ws + (1u << 20) + 65536);       // 64 KB
    unsigned short* w2_p  = (unsigned short*)(ws + (1u << 20) + 131072);      // 128 KB
    unsigned short* w1d_f = (unsigned short*)(ws + (1u << 20) + 262144);      // 8 KB
    unsigned short* b2_f  = (unsigned short*)(ws + (1u << 20) + 270336);      // 8 KB

    pack_all<<<256, 256, 0, stream>>>(W1, W2, b2, w1c_p, w1b_p, w2_p, w1d_f, b2_f);
    precompute_pa<<<BN * 2, 256, 0, stream>>>(node, W1, b1, PA);
    edge_main<<<dim3(BN / 128, BN, 2), 256, 0, stream>>>(
        node, euclid, W3, b3, PA, w1c_p, w1b_p, w2_p, w1d_f, b2_f, out);
    symmetrize<<<dim3(BN / 32, BN / 32, 2), dim3(32, 32), 0, stream>>>(out);
}